// Round 7
// 378.372 us; speedup vs baseline: 1.0587x; 1.0587x over previous
//
#include <hip/hip_runtime.h>

// MeanAggregator: out[b,d] = mean_k table[neighs[b,k], d]
// B=50000, K=32, D=128, fp32 table/out, int32 idx.
//
// R5 theory: the 152us / 2.8 TB/s plateau is a random-gather latency-capacity
// roofline: per-CU in-flight bytes (~4KB) / HBM-miss latency (~375ns) = 2.8 TB/s.
// More concurrency can't help (demand already >> cap); fewer bytes alone didn't
// (round-3). Fix the LATENCY: per-half-wave bitonic sort of the 32 neighbor ids
// + persistent all-resident grid => every wave sweeps the table in ascending
// order in lockstep. At any instant all waves touch a ~50-80MB moving window,
// so row re-reads (70% of gathers) hit L3 instead of HBM, and FETCH_SIZE drops
// toward the ~252MB unique-row floor.
//
// Structure: 8 node-pairs per wave (lanes 0-31 even node, 32-63 odd node),
// 3125 waves = 782 blocks, all co-resident (launch_bounds(256,4), no LDS).
// Per k-rank: 8 dwordx4 row loads (1KB each) double-buffered, 8 outstanding.
//
// (R11 = R5 resubmitted verbatim: rounds 5-10 all failed with
// GPUAcquisitionTimeout — infra errors, no counters, no signal, no reason
// to change the kernel.)

constexpr int BATCH  = 50000;
constexpr int DEGREE = 32;
constexpr int D_FEAT = 128;
constexpr int PW     = 8;                        // node-pairs per wave (16 nodes)
constexpr int NPAIRS = BATCH / 2;                // 25000
constexpr int WAVES  = (NPAIRS + PW - 1) / PW;   // 3125 (exact: 3125*8 == 25000)
constexpr int BLOCKS = (WAVES + 3) / 4;          // 782

typedef float f32x4 __attribute__((ext_vector_type(4)));

__global__ __launch_bounds__(256, 4) void MeanAggregator_841813590039_kernel(
    const int* __restrict__ neighs,     // [B, K] int32
    const float* __restrict__ table,    // [N, D] fp32
    float* __restrict__ out)            // [B, D] fp32
{
    const int wave = blockIdx.x * 4 + (threadIdx.x >> 6);
    const int lane = threadIdx.x & 63;
    const int col  = lane & 31;          // float4 column group (16B each)
    const int half = lane & 32;          // 0 / 32: which node of the pair

    if (wave >= WAVES) return;           // 3 tail waves do nothing

    const int pair0 = wave * PW;

    // Coalesced index load: pair i's 64 ids (32 per node) in one 4B/lane load.
    int rows[PW];
    #pragma unroll
    for (int i = 0; i < PW; ++i)
        rows[i] = neighs[(size_t)(pair0 + i) * (2 * DEGREE) + lane];

    // Bitonic sort ascending within each 32-lane half (xor masks <32 never
    // cross the half boundary). Permutation of the multiset -> mean unchanged.
    #pragma unroll
    for (int i = 0; i < PW; ++i) {
        int v = rows[i];
        #pragma unroll
        for (int size = 2; size <= 32; size <<= 1) {
            #pragma unroll
            for (int stride = size >> 1; stride > 0; stride >>= 1) {
                const int  pv    = __shfl_xor(v, stride, 64);
                const bool up    = ((col & size) == 0);
                const bool lower = ((col & stride) == 0);
                const int  mn    = (v < pv) ? v : pv;
                const int  mx    = (v < pv) ? pv : v;
                v = (lower == up) ? mn : mx;
            }
        }
        rows[i] = v;
    }

    // k-th smallest row of MY half for pair j: broadcast from lane (half + k).
    #define LOADKJ(j, k) \
        reinterpret_cast<const f32x4*>( \
            table + (size_t)__shfl(rows[(j)], half + (k), 64) * D_FEAT)[col]

    f32x4 acc[PW];
    #pragma unroll
    for (int j = 0; j < PW; ++j) acc[j] = f32x4{0.f, 0.f, 0.f, 0.f};

    f32x4 buf0[PW], buf1[PW];

    // Prologue: issue rank 0 (8 loads, 8KB in flight).
    #pragma unroll
    for (int j = 0; j < PW; ++j) buf0[j] = LOADKJ(j, 0);

    // Steady state: issue rank k+1, consume rank k. Fully unrolled so the
    // (k&1) buffer select folds to registers (no scratch).
    #pragma unroll
    for (int k = 0; k < DEGREE - 1; ++k) {
        f32x4* cur = (k & 1) ? buf1 : buf0;
        f32x4* nxt = (k & 1) ? buf0 : buf1;
        #pragma unroll
        for (int j = 0; j < PW; ++j) nxt[j] = LOADKJ(j, k + 1);
        #pragma unroll
        for (int j = 0; j < PW; ++j) acc[j] += cur[j];
    }
    // Epilogue: rank 31 lives in buf1 (k=30 wrote nxt=buf1).
    #pragma unroll
    for (int j = 0; j < PW; ++j) acc[j] += buf1[j];

    #undef LOADKJ

    const float inv = 1.0f / (float)DEGREE;

    // Lane L writes cols [4*col .. 4*col+3] of its node; 512B contiguous
    // per half-wave, never re-read -> nontemporal (keeps L3 window clean).
    #pragma unroll
    for (int i = 0; i < PW; ++i) {
        const int node = (pair0 + i) * 2 + (half >> 5);
        f32x4 v = acc[i];
        v *= inv;
        __builtin_nontemporal_store(
            v, reinterpret_cast<f32x4*>(out + (size_t)node * D_FEAT) + col);
    }
}

extern "C" void kernel_launch(void* const* d_in, const int* in_sizes, int n_in,
                              void* d_out, int out_size, void* d_ws, size_t ws_size,
                              hipStream_t stream) {
    const int*   neighs = (const int*)d_in[0];
    const float* table  = (const float*)d_in[1];
    float*       out    = (float*)d_out;

    // 782 blocks x 4 waves = 3128 waves; 3125 active, all co-resident
    // (<=4 blocks/CU, VGPR-capped by launch_bounds, zero LDS).
    MeanAggregator_841813590039_kernel<<<BLOCKS, 256, 0, stream>>>(neighs, table, out);
}